// Round 6
// baseline (1272.680 us; speedup 1.0000x reference)
//
#include <hip/hip_runtime.h>
#include <hip/hip_bf16.h>

#define N_NODES 100000
#define N_EDGES 1600000
#define D 128
#define NB 1563           // ceil(100000/64) buckets of 64 rows
#define CAP 256           // slots per (bucket, xcd-slice) sub-window
#define OCAP 8192         // overflow capacity (statistically never used)

typedef short  s8v  __attribute__((ext_vector_type(8)));
typedef float  f4v  __attribute__((ext_vector_type(4)));

__device__ __forceinline__ ushort f2bf(float f) {
    uint u = __float_as_uint(f);
    return (ushort)((u + 0x7FFFu + ((u >> 16) & 1u)) >> 16);
}
__device__ __forceinline__ float bflo(uint u) { return __uint_as_float(u << 16); }
__device__ __forceinline__ float bfhi(uint u) { return __uint_as_float(u & 0xFFFF0000u); }

// ---------------------------------------------------------------------------
// wt[n][k] = bf16(w[k][n])
// ---------------------------------------------------------------------------
__global__ __launch_bounds__(256) void k_wt(const float* __restrict__ w,
                                            ushort* __restrict__ wt) {
    int i = blockIdx.x * 256 + threadIdx.x;
    if (i < D * D) {
        int k = i >> 7, n = i & 127;
        wt[n * D + k] = f2bf(w[i]);
    }
}

// ---------------------------------------------------------------------------
// supb = bf16( X @ W )  via MFMA 16x16x32 bf16  (validated rounds 3/5)
// ---------------------------------------------------------------------------
__global__ __launch_bounds__(256, 2) void k_gemm(const float* __restrict__ x,
                                                 const ushort* __restrict__ wt,
                                                 ushort* __restrict__ supb) {
    __shared__ int4 Bl4[2048];            // 32 KB
    char* Bl = (char*)Bl4;

    const int t    = threadIdx.x;
    const int lane = t & 63;
    const int w    = t >> 6;
    const int row0 = blockIdx.x * 128;

    const int4* g = (const int4*)wt;
    #pragma unroll
    for (int i = 0; i < 8; ++i) {
        int idx = t + i * 256;
        int n = idx >> 4, c = idx & 15;
        *(int4*)(Bl + ((n * 256 + c * 16) ^ ((n & 7) << 4))) = g[idx];
    }
    __syncthreads();

    f4v acc[2][8] = {};
    const int arow = row0 + w * 32 + (lane & 15);
    const int kb   = (lane >> 4) * 8;

    #pragma unroll
    for (int ks = 0; ks < 4; ++ks) {
        s8v a[2];
        #pragma unroll
        for (int m = 0; m < 2; ++m) {
            int r = arow + m * 16;
            float4 f0 = make_float4(0.f, 0.f, 0.f, 0.f);
            float4 f1 = make_float4(0.f, 0.f, 0.f, 0.f);
            if (r < N_NODES) {
                const float4* p = (const float4*)(x + (size_t)r * D + ks * 32 + kb);
                f0 = p[0];
                f1 = p[1];
            }
            s8v av;
            av[0] = (short)f2bf(f0.x); av[1] = (short)f2bf(f0.y);
            av[2] = (short)f2bf(f0.z); av[3] = (short)f2bf(f0.w);
            av[4] = (short)f2bf(f1.x); av[5] = (short)f2bf(f1.y);
            av[6] = (short)f2bf(f1.z); av[7] = (short)f2bf(f1.w);
            a[m] = av;
        }
        #pragma unroll
        for (int n = 0; n < 8; ++n) {
            int brow = n * 16 + (lane & 15);
            s8v b = *(s8v*)(Bl + ((brow * 256 + (ks * 32 + kb) * 2) ^ ((brow & 7) << 4)));
            acc[0][n] = __builtin_amdgcn_mfma_f32_16x16x32_bf16(a[0], b, acc[0][n], 0, 0, 0);
            acc[1][n] = __builtin_amdgcn_mfma_f32_16x16x32_bf16(a[1], b, acc[1][n], 0, 0, 0);
        }
    }

    __syncthreads();
    char* E = Bl + w * 8192;
    #pragma unroll
    for (int m = 0; m < 2; ++m)
        #pragma unroll
        for (int n = 0; n < 8; ++n)
            #pragma unroll
            for (int r = 0; r < 4; ++r) {
                int rl  = m * 16 + ((lane >> 4) << 2) + r;
                int col = n * 16 + (lane & 15);
                *(ushort*)(E + ((rl * 256 + col * 2) ^ ((rl & 7) << 4))) =
                    f2bf(acc[m][n][r]);
            }
    __syncthreads();
    #pragma unroll
    for (int i = 0; i < 8; ++i) {
        int idx = lane + i * 64;
        int rl = idx >> 4, c = idx & 15;
        int4 v = *(int4*)(E + ((rl * 256 + c * 16) ^ ((rl & 7) << 4)));
        int grow = row0 + w * 32 + rl;
        if (grow < N_NODES)
            *(int4*)((char*)supb + (size_t)grow * 256 + c * 16) = v;
    }
}

// ---------------------------------------------------------------------------
// zero cursors (per-call re-init; harness does not re-poison between replays)
// ---------------------------------------------------------------------------
__global__ __launch_bounds__(256) void k_zero(int* __restrict__ bcur,
                                              int* __restrict__ ocur) {
    int i = blockIdx.x * 256 + threadIdx.x;
    if (i < NB * 8) bcur[i] = 0;
    if (i == 0) *ocur = 0;
}

// ---------------------------------------------------------------------------
// Partition edges into (bucket=row/64, xcd=blockIdx&7) sub-windows.
// Blocks round-robin over XCDs, so a sub-window's 64B lines are written by
// a single XCD's L2 -> full-line writebacks (the round-5 fix).
// meta = (local_row<<17) | col   (col < 2^17, local_row < 64)
// ---------------------------------------------------------------------------
__global__ __launch_bounds__(256) void k_part(const int* __restrict__ er,
                                              const int* __restrict__ ec,
                                              const float* __restrict__ ev,
                                              int* __restrict__ bcur,
                                              int2* __restrict__ tmp,
                                              int* __restrict__ ocur,
                                              int4* __restrict__ ovf) {
    int e = blockIdx.x * 256 + threadIdx.x;
    if (e >= N_EDGES) return;
    int   r = er[e];
    int   c = ec[e];
    float v = ev[e];
    int idx = (r >> 6) * 8 + (blockIdx.x & 7);
    int p = atomicAdd(&bcur[idx], 1);
    if (p < CAP) {
        tmp[idx * CAP + p] = make_int2(((r & 63) << 17) | c, __float_as_int(v));
    } else {
        int o = atomicAdd(ocur, 1);
        if (o < OCAP) ovf[o] = make_int4(r, c, __float_as_int(v), 0);
    }
}

// ---------------------------------------------------------------------------
// Bucket SpMM: one block per 64-row bucket. Accumulate into a 32KB LDS fp32
// tile with ds_add_f32 (2-way bank aliasing = free), consume the 8 unsorted
// sub-windows directly (no CSR, no sort). Epilogue: +bias, coalesced store.
// ---------------------------------------------------------------------------
__global__ __launch_bounds__(256) void k_spmm(const ushort* __restrict__ supb,
                                              const int* __restrict__ bcur,
                                              const int2* __restrict__ tmp,
                                              const float* __restrict__ bias,
                                              float* __restrict__ out) {
    __shared__ float tile[64][128];   // 32 KB
    __shared__ float bs[128];
    const int b  = blockIdx.x;
    const int r0 = b * 64;
    const int t  = threadIdx.x;

    float4* t4 = (float4*)&tile[0][0];
    #pragma unroll
    for (int i = t; i < 64 * 32; i += 256) t4[i] = make_float4(0.f, 0.f, 0.f, 0.f);
    if (t < 128) bs[t] = bias[t];
    __syncthreads();

    const int w    = t >> 6;
    const int lane = t & 63;
    const uint* S  = (const uint*)supb;   // 64 uints (=128 bf16) per row

    for (int x = 0; x < 8; ++x) {
        const int idx = b * 8 + x;
        int n = bcur[idx];
        if (n > CAP) n = CAP;
        const int2* win = tmp + (size_t)idx * CAP;

        int j = w;
        // 4 edges in flight per wave (waves stride 4)
        for (; j + 12 < n; j += 16) {
            int2 e0 = win[j];
            int2 e1 = win[j + 4];
            int2 e2 = win[j + 8];
            int2 e3 = win[j + 12];
            uint s0 = S[(size_t)(e0.x & 0x1FFFF) * 64 + lane];
            uint s1 = S[(size_t)(e1.x & 0x1FFFF) * 64 + lane];
            uint s2 = S[(size_t)(e2.x & 0x1FFFF) * 64 + lane];
            uint s3 = S[(size_t)(e3.x & 0x1FFFF) * 64 + lane];
            float v0 = __int_as_float(e0.y), v1 = __int_as_float(e1.y);
            float v2 = __int_as_float(e2.y), v3 = __int_as_float(e3.y);
            int r0i = e0.x >> 17, r1i = e1.x >> 17;
            int r2i = e2.x >> 17, r3i = e3.x >> 17;
            atomicAdd(&tile[r0i][2 * lane],     v0 * bflo(s0));
            atomicAdd(&tile[r0i][2 * lane + 1], v0 * bfhi(s0));
            atomicAdd(&tile[r1i][2 * lane],     v1 * bflo(s1));
            atomicAdd(&tile[r1i][2 * lane + 1], v1 * bfhi(s1));
            atomicAdd(&tile[r2i][2 * lane],     v2 * bflo(s2));
            atomicAdd(&tile[r2i][2 * lane + 1], v2 * bfhi(s2));
            atomicAdd(&tile[r3i][2 * lane],     v3 * bflo(s3));
            atomicAdd(&tile[r3i][2 * lane + 1], v3 * bfhi(s3));
        }
        for (; j < n; j += 4) {
            int2 e0 = win[j];
            uint s0 = S[(size_t)(e0.x & 0x1FFFF) * 64 + lane];
            float v0 = __int_as_float(e0.y);
            int r0i = e0.x >> 17;
            atomicAdd(&tile[r0i][2 * lane],     v0 * bflo(s0));
            atomicAdd(&tile[r0i][2 * lane + 1], v0 * bfhi(s0));
        }
    }
    __syncthreads();

    // epilogue: out[r0+row] = tile[row] + bias, coalesced float4
    for (int i = t; i < 64 * 32; i += 256) {
        int row = i >> 5, cg = i & 31;
        int gr = r0 + row;
        if (gr < N_NODES) {
            float4 v = *(float4*)&tile[row][cg * 4];
            v.x += bs[cg * 4 + 0];
            v.y += bs[cg * 4 + 1];
            v.z += bs[cg * 4 + 2];
            v.w += bs[cg * 4 + 3];
            *(float4*)(out + (size_t)gr * D + cg * 4) = v;
        }
    }
}

// ---------------------------------------------------------------------------
// Overflow cleanup (statistically empty): one wave per spilled edge,
// global fp32 atomics into out. Runs after k_spmm.
// ---------------------------------------------------------------------------
__global__ __launch_bounds__(256) void k_ofl(const ushort* __restrict__ supb,
                                             const int4* __restrict__ ovf,
                                             const int* __restrict__ ocur,
                                             float* __restrict__ out) {
    int n = *ocur;
    if (n > OCAP) n = OCAP;
    const int lane = threadIdx.x & 63;
    const uint* S = (const uint*)supb;
    for (int e = (blockIdx.x * 256 + threadIdx.x) >> 6; e < n; e += 64) {
        int4 rec = ovf[e];
        uint s = S[(size_t)rec.y * 64 + lane];
        float v = __int_as_float(rec.z);
        atomicAdd(&out[(size_t)rec.x * D + 2 * lane],     v * bflo(s));
        atomicAdd(&out[(size_t)rec.x * D + 2 * lane + 1], v * bfhi(s));
    }
}

extern "C" void kernel_launch(void* const* d_in, const int* in_sizes, int n_in,
                              void* d_out, int out_size, void* d_ws, size_t ws_size,
                              hipStream_t stream) {
    const float* x    = (const float*)d_in[0];
    const float* w    = (const float*)d_in[1];
    const float* bias = (const float*)d_in[2];
    const float* ev   = (const float*)d_in[3];
    const int*   er   = (const int*)d_in[4];
    const int*   ec   = (const int*)d_in[5];
    float* out = (float*)d_out;

    // workspace layout (16B aligned), ~51.4 MB
    char* ws = (char*)d_ws;
    ushort* supb = (ushort*)(ws);                  // 25,600,000
    ushort* wt   = (ushort*)(ws + 25600000);       //     32,768
    int*    bcur = (int*)   (ws + 25632768);       //     50,048 (NB*8 ints)
    int*    ocur = (int*)   (ws + 25682816);       //         64
    int4*   ovf  = (int4*)  (ws + 25682880);       //    131,072
    int2*   tmp  = (int2*)  (ws + 25813952);       // 25,608,192 (NB*8*CAP*8B)

    k_wt  <<<64, 256, 0, stream>>>(w, wt);
    k_gemm<<<(N_NODES + 127) / 128, 256, 0, stream>>>(x, wt, supb);

    k_zero<<<(NB * 8 + 255) / 256, 256, 0, stream>>>(bcur, ocur);
    k_part<<<(N_EDGES + 255) / 256, 256, 0, stream>>>(er, ec, ev, bcur, tmp,
                                                      ocur, ovf);

    k_spmm<<<NB, 256, 0, stream>>>(supb, bcur, tmp, bias, out);
    k_ofl <<<16, 256, 0, stream>>>(supb, ovf, ocur, out);
}

// Round 7
// 181.067 us; speedup vs baseline: 7.0288x; 7.0288x over previous
//
#include <hip/hip_runtime.h>
#include <hip/hip_bf16.h>

#define N_NODES 100000
#define N_EDGES 1600000
#define D 128
#define NBUCK 782        // ceil(100000/128) buckets of 128 rows
#define CAP 352          // slots per (bucket, xcd-slice) sub-window
#define BCAP (8 * CAP)   // scv capacity per bucket
#define OCAP 8192        // overflow capacity (statistically never used)

typedef short  s8v  __attribute__((ext_vector_type(8)));
typedef float  f4v  __attribute__((ext_vector_type(4)));

__device__ __forceinline__ ushort f2bf(float f) {
    uint u = __float_as_uint(f);
    return (ushort)((u + 0x7FFFu + ((u >> 16) & 1u)) >> 16);
}
__device__ __forceinline__ float bflo(uint u) { return __uint_as_float(u << 16); }
__device__ __forceinline__ float bfhi(uint u) { return __uint_as_float(u & 0xFFFF0000u); }

// ---------------------------------------------------------------------------
// wt[n][k] = bf16(w[k][n])
// ---------------------------------------------------------------------------
__global__ __launch_bounds__(256) void k_wt(const float* __restrict__ w,
                                            ushort* __restrict__ wt) {
    int i = blockIdx.x * 256 + threadIdx.x;
    if (i < D * D) {
        int k = i >> 7, n = i & 127;
        wt[n * D + k] = f2bf(w[i]);
    }
}

// ---------------------------------------------------------------------------
// supb = bf16( X @ W )  via MFMA 16x16x32 bf16  (validated rounds 3/5)
// ---------------------------------------------------------------------------
__global__ __launch_bounds__(256, 2) void k_gemm(const float* __restrict__ x,
                                                 const ushort* __restrict__ wt,
                                                 ushort* __restrict__ supb) {
    __shared__ int4 Bl4[2048];            // 32 KB
    char* Bl = (char*)Bl4;

    const int t    = threadIdx.x;
    const int lane = t & 63;
    const int w    = t >> 6;
    const int row0 = blockIdx.x * 128;

    const int4* g = (const int4*)wt;
    #pragma unroll
    for (int i = 0; i < 8; ++i) {
        int idx = t + i * 256;
        int n = idx >> 4, c = idx & 15;
        *(int4*)(Bl + ((n * 256 + c * 16) ^ ((n & 7) << 4))) = g[idx];
    }
    __syncthreads();

    f4v acc[2][8] = {};
    const int arow = row0 + w * 32 + (lane & 15);
    const int kb   = (lane >> 4) * 8;

    #pragma unroll
    for (int ks = 0; ks < 4; ++ks) {
        s8v a[2];
        #pragma unroll
        for (int m = 0; m < 2; ++m) {
            int r = arow + m * 16;
            float4 f0 = make_float4(0.f, 0.f, 0.f, 0.f);
            float4 f1 = make_float4(0.f, 0.f, 0.f, 0.f);
            if (r < N_NODES) {
                const float4* p = (const float4*)(x + (size_t)r * D + ks * 32 + kb);
                f0 = p[0];
                f1 = p[1];
            }
            s8v av;
            av[0] = (short)f2bf(f0.x); av[1] = (short)f2bf(f0.y);
            av[2] = (short)f2bf(f0.z); av[3] = (short)f2bf(f0.w);
            av[4] = (short)f2bf(f1.x); av[5] = (short)f2bf(f1.y);
            av[6] = (short)f2bf(f1.z); av[7] = (short)f2bf(f1.w);
            a[m] = av;
        }
        #pragma unroll
        for (int n = 0; n < 8; ++n) {
            int brow = n * 16 + (lane & 15);
            s8v b = *(s8v*)(Bl + ((brow * 256 + (ks * 32 + kb) * 2) ^ ((brow & 7) << 4)));
            acc[0][n] = __builtin_amdgcn_mfma_f32_16x16x32_bf16(a[0], b, acc[0][n], 0, 0, 0);
            acc[1][n] = __builtin_amdgcn_mfma_f32_16x16x32_bf16(a[1], b, acc[1][n], 0, 0, 0);
        }
    }

    __syncthreads();
    char* E = Bl + w * 8192;
    #pragma unroll
    for (int m = 0; m < 2; ++m)
        #pragma unroll
        for (int n = 0; n < 8; ++n)
            #pragma unroll
            for (int r = 0; r < 4; ++r) {
                int rl  = m * 16 + ((lane >> 4) << 2) + r;
                int col = n * 16 + (lane & 15);
                *(ushort*)(E + ((rl * 256 + col * 2) ^ ((rl & 7) << 4))) =
                    f2bf(acc[m][n][r]);
            }
    __syncthreads();
    #pragma unroll
    for (int i = 0; i < 8; ++i) {
        int idx = lane + i * 64;
        int rl = idx >> 4, c = idx & 15;
        int4 v = *(int4*)(E + ((rl * 256 + c * 16) ^ ((rl & 7) << 4)));
        int grow = row0 + w * 32 + rl;
        if (grow < N_NODES)
            *(int4*)((char*)supb + (size_t)grow * 256 + c * 16) = v;
    }
}

// ---------------------------------------------------------------------------
// zero cursors (per-call re-init)
// ---------------------------------------------------------------------------
__global__ __launch_bounds__(256) void k_zero(int* __restrict__ bcur,
                                              int* __restrict__ ocur) {
    int i = blockIdx.x * 256 + threadIdx.x;
    if (i < NBUCK * 8 * 16) bcur[i] = 0;
    if (i == 0) *ocur = 0;
}

// ---------------------------------------------------------------------------
// Partition edges into (bucket=row>>7, slice=blockIdx&7) sub-windows.
// Blocks round-robin over the 8 XCDs, so one sub-window's 64B lines are
// dirtied by a single XCD's L2 -> full-line writebacks (round-5 lesson).
// meta = (local_row<<17) | col   (7 + 17 bits)
// Cursors padded to 64B to avoid line ping-pong.
// ---------------------------------------------------------------------------
__global__ __launch_bounds__(256) void k_part(const int* __restrict__ er,
                                              const int* __restrict__ ec,
                                              const float* __restrict__ ev,
                                              int* __restrict__ bcur,
                                              int2* __restrict__ tmp,
                                              int* __restrict__ ocur,
                                              int4* __restrict__ ovf) {
    int e = blockIdx.x * 256 + threadIdx.x;
    if (e >= N_EDGES) return;
    int   r = er[e];
    int   c = ec[e];
    float v = ev[e];
    int idx = (r >> 7) * 8 + (blockIdx.x & 7);
    int p = atomicAdd(&bcur[idx * 16], 1);
    if (p < CAP) {
        tmp[(size_t)idx * CAP + p] = make_int2(((r & 127) << 17) | c,
                                               __float_as_int(v));
    } else {
        int o = atomicAdd(ocur, 1);
        if (o < OCAP) ovf[o] = make_int4(r, c, __float_as_int(v), 0);
    }
}

// ---------------------------------------------------------------------------
// Per-bucket CSR build: one block per bucket. LDS histogram over the 8
// sub-windows, 128-wide scan, place edges into scv[b*BCAP ...], emit per-row
// (start,end) to rowrg. Replaces hist + 3 scans + global-cursor scatter.
// ---------------------------------------------------------------------------
__global__ __launch_bounds__(256) void k_sort(const int2* __restrict__ tmp,
                                              const int* __restrict__ bcur,
                                              int2* __restrict__ scv,
                                              int2* __restrict__ rowrg) {
    __shared__ int hist[128];
    __shared__ int ex[128];     // exclusive start per local row
    __shared__ int cur[128];
    __shared__ int wn[8];
    const int tx = (int)threadIdx.x;
    const int b  = blockIdx.x;
    const int r0 = b << 7;
    const int base = b * BCAP;

    if (tx < 128) { hist[tx] = 0; cur[tx] = 0; }
    if (tx < 8) {
        int n = bcur[(b * 8 + tx) * 16];
        wn[tx] = (n > CAP) ? CAP : n;
    }
    __syncthreads();

    // pass 1: histogram of local rows
    for (int x = 0; x < 8; ++x) {
        const int2* win = tmp + (size_t)(b * 8 + x) * CAP;
        const int n = wn[x];
        for (int i = tx; i < n; i += 256)
            atomicAdd(&hist[win[i].x >> 17], 1);
    }
    __syncthreads();

    // inclusive scan of hist (Hillis-Steele, barriers hit by all threads)
    int v = (tx < 128) ? hist[tx] : 0;
    if (tx < 128) ex[tx] = v;
    __syncthreads();
    for (int off = 1; off < 128; off <<= 1) {
        int t = 0;
        if (tx < 128 && tx >= off) t = ex[tx - off];
        __syncthreads();
        if (tx < 128) ex[tx] += t;
        __syncthreads();
    }
    // inclusive -> exclusive; emit rowrg
    if (tx < 128) {
        int incl = ex[tx];
        int e0   = incl - v;
        if (r0 + tx < N_NODES)
            rowrg[r0 + tx] = make_int2(base + e0, base + incl);
        ex[tx] = e0;
    }
    __syncthreads();

    // pass 2: place
    for (int x = 0; x < 8; ++x) {
        const int2* win = tmp + (size_t)(b * 8 + x) * CAP;
        const int n = wn[x];
        for (int i = tx; i < n; i += 256) {
            int2 t = win[i];
            int lr = t.x >> 17;
            int p  = ex[lr] + atomicAdd(&cur[lr], 1);
            scv[base + p] = make_int2(t.x & 0x1FFFF, t.y);
        }
    }
}

// ---------------------------------------------------------------------------
// CSR SpMM: one wave per row; half-wave per edge; 8 edges/iter (4 uint2
// gathers in flight per lane); __shfl_xor(32) fold; float4 store with bias.
// ---------------------------------------------------------------------------
__global__ __launch_bounds__(256) void k_spmm(const ushort* __restrict__ supb,
                                              const int2* __restrict__ rowrg,
                                              const int2* __restrict__ scv,
                                              const float* __restrict__ bias,
                                              float* __restrict__ out) {
    const int row = blockIdx.x * 4 + (threadIdx.x >> 6);
    if (row >= N_NODES) return;
    const int lane = threadIdx.x & 63;
    const int sub  = lane >> 5;
    const int sl   = lane & 31;

    const int2 rg = rowrg[row];
    int j = rg.x;
    const int end = rg.y;
    const uint2* S = (const uint2*)supb;

    float4 acc = make_float4(0.f, 0.f, 0.f, 0.f);

    // 8 edges per iteration (4 per half-wave)
    for (; j + 7 < end; j += 8) {
        int2 e0 = scv[j + sub];
        int2 e1 = scv[j + 2 + sub];
        int2 e2 = scv[j + 4 + sub];
        int2 e3 = scv[j + 6 + sub];
        uint2 s0 = S[(size_t)e0.x * 32 + sl];
        uint2 s1 = S[(size_t)e1.x * 32 + sl];
        uint2 s2 = S[(size_t)e2.x * 32 + sl];
        uint2 s3 = S[(size_t)e3.x * 32 + sl];
        float v0 = __int_as_float(e0.y), v1 = __int_as_float(e1.y);
        float v2 = __int_as_float(e2.y), v3 = __int_as_float(e3.y);
        acc.x += v0 * bflo(s0.x) + v1 * bflo(s1.x) + v2 * bflo(s2.x) + v3 * bflo(s3.x);
        acc.y += v0 * bfhi(s0.x) + v1 * bfhi(s1.x) + v2 * bfhi(s2.x) + v3 * bfhi(s3.x);
        acc.z += v0 * bflo(s0.y) + v1 * bflo(s1.y) + v2 * bflo(s2.y) + v3 * bflo(s3.y);
        acc.w += v0 * bfhi(s0.y) + v1 * bfhi(s1.y) + v2 * bfhi(s2.y) + v3 * bfhi(s3.y);
    }
    // pair tail (clamped, predicated)
    for (; j < end; j += 2) {
        int jj = j + sub;
        if (jj > end - 1) jj = end - 1;
        int2 e = scv[jj];
        float v = (j + sub < end) ? __int_as_float(e.y) : 0.f;
        uint2 s = S[(size_t)e.x * 32 + sl];
        acc.x += v * bflo(s.x);
        acc.y += v * bfhi(s.x);
        acc.z += v * bflo(s.y);
        acc.w += v * bfhi(s.y);
    }

    acc.x += __shfl_xor(acc.x, 32);
    acc.y += __shfl_xor(acc.y, 32);
    acc.z += __shfl_xor(acc.z, 32);
    acc.w += __shfl_xor(acc.w, 32);

    if (sub == 0) {
        float4 bb = *(const float4*)(bias + 4 * sl);
        acc.x += bb.x; acc.y += bb.y; acc.z += bb.z; acc.w += bb.w;
        *(float4*)(out + (size_t)row * D + 4 * sl) = acc;
    }
}

// ---------------------------------------------------------------------------
// Overflow cleanup (statistically empty), after k_spmm: global atomics.
// ---------------------------------------------------------------------------
__global__ __launch_bounds__(256) void k_ofl(const ushort* __restrict__ supb,
                                             const int4* __restrict__ ovf,
                                             const int* __restrict__ ocur,
                                             float* __restrict__ out) {
    int n = *ocur;
    if (n > OCAP) n = OCAP;
    const int lane = threadIdx.x & 63;
    const uint* S = (const uint*)supb;
    for (int e = (blockIdx.x * 256 + threadIdx.x) >> 6; e < n; e += 64) {
        int4 rec = ovf[e];
        uint s = S[(size_t)rec.y * 64 + lane];
        float v = __int_as_float(rec.z);
        atomicAdd(&out[(size_t)rec.x * D + 2 * lane],     v * bflo(s));
        atomicAdd(&out[(size_t)rec.x * D + 2 * lane + 1], v * bfhi(s));
    }
}

extern "C" void kernel_launch(void* const* d_in, const int* in_sizes, int n_in,
                              void* d_out, int out_size, void* d_ws, size_t ws_size,
                              hipStream_t stream) {
    const float* x    = (const float*)d_in[0];
    const float* w    = (const float*)d_in[1];
    const float* bias = (const float*)d_in[2];
    const float* ev   = (const float*)d_in[3];
    const int*   er   = (const int*)d_in[4];
    const int*   ec   = (const int*)d_in[5];
    float* out = (float*)d_out;

    // workspace layout (16B aligned), ~62.2 MB
    char* ws = (char*)d_ws;
    ushort* supb  = (ushort*)(ws);                 // 25,600,000
    ushort* wt    = (ushort*)(ws + 25600000);      //     32,768
    int*    bcur  = (int*)   (ws + 25632768);      //    400,384 (NBUCK*8*16 ints)
    int*    ocur  = (int*)   (ws + 26033152);      //         64
    int4*   ovf   = (int4*)  (ws + 26033216);      //    131,072
    int2*   tmp   = (int2*)  (ws + 26164288);      // 17,614,848 (NBUCK*8*CAP*8)
    int2*   scv   = (int2*)  (ws + 43779136);      // 17,614,848 (NBUCK*BCAP*8)
    int2*   rowrg = (int2*)  (ws + 61393984);      //    800,000
    // end ~62,193,984

    k_wt  <<<64, 256, 0, stream>>>(w, wt);
    k_gemm<<<(N_NODES + 127) / 128, 256, 0, stream>>>(x, wt, supb);

    k_zero<<<(NBUCK * 8 * 16 + 255) / 256, 256, 0, stream>>>(bcur, ocur);
    k_part<<<(N_EDGES + 255) / 256, 256, 0, stream>>>(er, ec, ev, bcur, tmp,
                                                      ocur, ovf);
    k_sort<<<NBUCK, 256, 0, stream>>>(tmp, bcur, scv, rowrg);

    k_spmm<<<(N_NODES + 3) / 4, 256, 0, stream>>>(supb, rowrg, scv, bias, out);
    k_ofl <<<16, 256, 0, stream>>>(supb, ovf, ocur, out);
}

// Round 8
// 140.107 us; speedup vs baseline: 9.0836x; 1.2923x over previous
//
#include <hip/hip_runtime.h>
#include <hip/hip_bf16.h>

#define N_NODES 100000
#define N_EDGES 1600000
#define D 128
#define NBUCK 782        // ceil(100000/128) buckets of 128 rows
#define G 320            // partition blocks
#define EPB 5000         // edges per partition block (320*5000 = 1.6M)
#define CAPG 16          // slots per (bucket, block) window = 128B, line-aligned
#define WSLOT (G * CAPG) // 5120 slots per bucket in tmp
#define EBCAP 2816       // LDS staging capacity in k_sort (bucket mean 2048, sigma 45)
#define OCAP 8192        // overflow capacity

typedef short  s8v  __attribute__((ext_vector_type(8)));
typedef float  f4v  __attribute__((ext_vector_type(4)));

__device__ __forceinline__ ushort f2bf(float f) {
    uint u = __float_as_uint(f);
    return (ushort)((u + 0x7FFFu + ((u >> 16) & 1u)) >> 16);
}
__device__ __forceinline__ float bflo(uint u) { return __uint_as_float(u << 16); }
__device__ __forceinline__ float bfhi(uint u) { return __uint_as_float(u & 0xFFFF0000u); }

// ---------------------------------------------------------------------------
// wt[n][k] = bf16(w[k][n]); also zeroes the overflow cursor (per-call re-init)
// ---------------------------------------------------------------------------
__global__ __launch_bounds__(256) void k_wt(const float* __restrict__ w,
                                            ushort* __restrict__ wt,
                                            int* __restrict__ ocur) {
    int i = blockIdx.x * 256 + threadIdx.x;
    if (i == 0) *ocur = 0;
    if (i < D * D) {
        int k = i >> 7, n = i & 127;
        wt[n * D + k] = f2bf(w[i]);
    }
}

// ---------------------------------------------------------------------------
// supb = bf16( X @ W )  via MFMA 16x16x32 bf16  (validated rounds 3/5/7)
// ---------------------------------------------------------------------------
__global__ __launch_bounds__(256, 2) void k_gemm(const float* __restrict__ x,
                                                 const ushort* __restrict__ wt,
                                                 ushort* __restrict__ supb) {
    __shared__ int4 Bl4[2048];            // 32 KB
    char* Bl = (char*)Bl4;

    const int t    = threadIdx.x;
    const int lane = t & 63;
    const int w    = t >> 6;
    const int row0 = blockIdx.x * 128;

    const int4* g = (const int4*)wt;
    #pragma unroll
    for (int i = 0; i < 8; ++i) {
        int idx = t + i * 256;
        int n = idx >> 4, c = idx & 15;
        *(int4*)(Bl + ((n * 256 + c * 16) ^ ((n & 7) << 4))) = g[idx];
    }
    __syncthreads();

    f4v acc[2][8] = {};
    const int arow = row0 + w * 32 + (lane & 15);
    const int kb   = (lane >> 4) * 8;

    #pragma unroll
    for (int ks = 0; ks < 4; ++ks) {
        s8v a[2];
        #pragma unroll
        for (int m = 0; m < 2; ++m) {
            int r = arow + m * 16;
            float4 f0 = make_float4(0.f, 0.f, 0.f, 0.f);
            float4 f1 = make_float4(0.f, 0.f, 0.f, 0.f);
            if (r < N_NODES) {
                const float4* p = (const float4*)(x + (size_t)r * D + ks * 32 + kb);
                f0 = p[0];
                f1 = p[1];
            }
            s8v av;
            av[0] = (short)f2bf(f0.x); av[1] = (short)f2bf(f0.y);
            av[2] = (short)f2bf(f0.z); av[3] = (short)f2bf(f0.w);
            av[4] = (short)f2bf(f1.x); av[5] = (short)f2bf(f1.y);
            av[6] = (short)f2bf(f1.z); av[7] = (short)f2bf(f1.w);
            a[m] = av;
        }
        #pragma unroll
        for (int n = 0; n < 8; ++n) {
            int brow = n * 16 + (lane & 15);
            s8v b = *(s8v*)(Bl + ((brow * 256 + (ks * 32 + kb) * 2) ^ ((brow & 7) << 4)));
            acc[0][n] = __builtin_amdgcn_mfma_f32_16x16x32_bf16(a[0], b, acc[0][n], 0, 0, 0);
            acc[1][n] = __builtin_amdgcn_mfma_f32_16x16x32_bf16(a[1], b, acc[1][n], 0, 0, 0);
        }
    }

    __syncthreads();
    char* E = Bl + w * 8192;
    #pragma unroll
    for (int m = 0; m < 2; ++m)
        #pragma unroll
        for (int n = 0; n < 8; ++n)
            #pragma unroll
            for (int r = 0; r < 4; ++r) {
                int rl  = m * 16 + ((lane >> 4) << 2) + r;
                int col = n * 16 + (lane & 15);
                *(ushort*)(E + ((rl * 256 + col * 2) ^ ((rl & 7) << 4))) =
                    f2bf(acc[m][n][r]);
            }
    __syncthreads();
    #pragma unroll
    for (int i = 0; i < 8; ++i) {
        int idx = lane + i * 64;
        int rl = idx >> 4, c = idx & 15;
        int4 v = *(int4*)(E + ((rl * 256 + c * 16) ^ ((rl & 7) << 4)));
        int grow = row0 + w * 32 + rl;
        if (grow < N_NODES)
            *(int4*)((char*)supb + (size_t)grow * 256 + c * 16) = v;
    }
}

// ---------------------------------------------------------------------------
// Block-private partition: block g bins its 5000 edges into private windows
// tmp[(b*G+g)*CAPG], cursors in LDS (no device atomics on the hot path).
// Each 128B window has exactly ONE writer block -> lines fill in one L2.
// meta = (local_row<<17) | col
// ---------------------------------------------------------------------------
__global__ __launch_bounds__(512) void k_part(const int* __restrict__ er,
                                              const int* __restrict__ ec,
                                              const float* __restrict__ ev,
                                              int2* __restrict__ tmp,
                                              int* __restrict__ counts,
                                              int* __restrict__ ocur,
                                              int4* __restrict__ ovf) {
    __shared__ int cur[NBUCK];
    const int tx = (int)threadIdx.x;
    const int g  = blockIdx.x;
    for (int i = tx; i < NBUCK; i += 512) cur[i] = 0;
    __syncthreads();

    const int base = g * EPB;
    for (int i = tx; i < EPB; i += 512) {
        int e = base + i;
        int   r = er[e];
        int   c = ec[e];
        float v = ev[e];
        int b = r >> 7;
        int p = atomicAdd(&cur[b], 1);
        if (p < CAPG) {
            tmp[(size_t)b * WSLOT + g * CAPG + p] =
                make_int2(((r & 127) << 17) | c, __float_as_int(v));
        } else {
            int o = atomicAdd(ocur, 1);
            if (o < OCAP) ovf[o] = make_int4(r, c, __float_as_int(v), 0);
        }
    }
    __syncthreads();
    for (int i = tx; i < NBUCK; i += 512) {
        int n = cur[i];
        counts[g * NBUCK + i] = (n > CAPG) ? CAPG : n;
    }
}

// ---------------------------------------------------------------------------
// Per-bucket CSR build, in-place: stage the bucket's G windows into LDS,
// histogram + scan + place back into tmp[b*WSLOT ...] (sorted by row),
// emit per-row (start,end). One block (320 threads) per bucket.
// ---------------------------------------------------------------------------
__global__ __launch_bounds__(320) void k_sort(int2* __restrict__ tmp,
                                              const int* __restrict__ counts,
                                              int2* __restrict__ rowrg,
                                              int* __restrict__ ocur,
                                              int4* __restrict__ ovf) {
    __shared__ int wn[G];
    __shared__ int wincl[G];
    __shared__ int hist[128], ex[128], cur[128];
    __shared__ int2 eb[EBCAP];
    const int tx = (int)threadIdx.x;
    const int b  = blockIdx.x;
    const int r0 = b << 7;

    int n = counts[tx * NBUCK + b];
    wn[tx] = n;
    wincl[tx] = n;
    if (tx < 128) { hist[tx] = 0; cur[tx] = 0; }
    __syncthreads();

    // inclusive scan over G=320 window counts
    for (int off = 1; off < G; off <<= 1) {
        int t = (tx >= off) ? wincl[tx - off] : 0;
        __syncthreads();
        wincl[tx] += t;
        __syncthreads();
    }
    const int cnt0 = wincl[G - 1];

    // stage window tx into eb
    {
        int o = wincl[tx] - wn[tx];
        const int2* win = tmp + ((size_t)b * G + tx) * CAPG;
        for (int k = 0; k < wn[tx]; ++k) {
            int idx = o + k;
            int2 t = win[k];
            if (idx < EBCAP) {
                eb[idx] = t;
            } else {
                int oo = atomicAdd(ocur, 1);
                if (oo < OCAP)
                    ovf[oo] = make_int4(r0 + (t.x >> 17), t.x & 0x1FFFF, t.y, 0);
            }
        }
    }
    __syncthreads();
    const int cnt = (cnt0 > EBCAP) ? EBCAP : cnt0;

    // histogram of local rows
    for (int i = tx; i < cnt; i += 320)
        atomicAdd(&hist[eb[i].x >> 17], 1);
    __syncthreads();

    // inclusive scan over 128 (all threads hit barriers)
    int hv = (tx < 128) ? hist[tx] : 0;
    if (tx < 128) ex[tx] = hv;
    __syncthreads();
    for (int off = 1; off < 128; off <<= 1) {
        int t = 0;
        if (tx < 128 && tx >= off) t = ex[tx - off];
        __syncthreads();
        if (tx < 128) ex[tx] += t;
        __syncthreads();
    }
    if (tx < 128) {
        int incl = ex[tx];
        int e0   = incl - hv;
        if (r0 + tx < N_NODES)
            rowrg[r0 + tx] = make_int2(b * WSLOT + e0, b * WSLOT + incl);
        ex[tx] = e0;
    }
    __syncthreads();

    // place (source fully staged in LDS -> safe to overwrite bucket range)
    int2* dst = tmp + (size_t)b * WSLOT;
    for (int i = tx; i < cnt; i += 320) {
        int2 t = eb[i];
        int lr = t.x >> 17;
        int p  = ex[lr] + atomicAdd(&cur[lr], 1);
        dst[p] = make_int2(t.x & 0x1FFFF, t.y);
    }
}

// ---------------------------------------------------------------------------
// CSR SpMM: one wave per row; half-wave per edge; 8 edges/iter; fold via
// __shfl_xor(32); float4 store with bias. (validated round 7)
// ---------------------------------------------------------------------------
__global__ __launch_bounds__(256) void k_spmm(const ushort* __restrict__ supb,
                                              const int2* __restrict__ rowrg,
                                              const int2* __restrict__ scv,
                                              const float* __restrict__ bias,
                                              float* __restrict__ out) {
    const int row = blockIdx.x * 4 + (threadIdx.x >> 6);
    if (row >= N_NODES) return;
    const int lane = threadIdx.x & 63;
    const int sub  = lane >> 5;
    const int sl   = lane & 31;

    const int2 rg = rowrg[row];
    int j = rg.x;
    const int end = rg.y;
    const uint2* S = (const uint2*)supb;

    float4 acc = make_float4(0.f, 0.f, 0.f, 0.f);

    for (; j + 7 < end; j += 8) {
        int2 e0 = scv[j + sub];
        int2 e1 = scv[j + 2 + sub];
        int2 e2 = scv[j + 4 + sub];
        int2 e3 = scv[j + 6 + sub];
        uint2 s0 = S[(size_t)e0.x * 32 + sl];
        uint2 s1 = S[(size_t)e1.x * 32 + sl];
        uint2 s2 = S[(size_t)e2.x * 32 + sl];
        uint2 s3 = S[(size_t)e3.x * 32 + sl];
        float v0 = __int_as_float(e0.y), v1 = __int_as_float(e1.y);
        float v2 = __int_as_float(e2.y), v3 = __int_as_float(e3.y);
        acc.x += v0 * bflo(s0.x) + v1 * bflo(s1.x) + v2 * bflo(s2.x) + v3 * bflo(s3.x);
        acc.y += v0 * bfhi(s0.x) + v1 * bfhi(s1.x) + v2 * bfhi(s2.x) + v3 * bfhi(s3.x);
        acc.z += v0 * bflo(s0.y) + v1 * bflo(s1.y) + v2 * bflo(s2.y) + v3 * bflo(s3.y);
        acc.w += v0 * bfhi(s0.y) + v1 * bfhi(s1.y) + v2 * bfhi(s2.y) + v3 * bfhi(s3.y);
    }
    for (; j < end; j += 2) {
        int jj = j + sub;
        if (jj > end - 1) jj = end - 1;
        int2 e = scv[jj];
        float v = (j + sub < end) ? __int_as_float(e.y) : 0.f;
        uint2 s = S[(size_t)e.x * 32 + sl];
        acc.x += v * bflo(s.x);
        acc.y += v * bfhi(s.x);
        acc.z += v * bflo(s.y);
        acc.w += v * bfhi(s.y);
    }

    acc.x += __shfl_xor(acc.x, 32);
    acc.y += __shfl_xor(acc.y, 32);
    acc.z += __shfl_xor(acc.z, 32);
    acc.w += __shfl_xor(acc.w, 32);

    if (sub == 0) {
        float4 bb = *(const float4*)(bias + 4 * sl);
        acc.x += bb.x; acc.y += bb.y; acc.z += bb.z; acc.w += bb.w;
        *(float4*)(out + (size_t)row * D + 4 * sl) = acc;
    }
}

// ---------------------------------------------------------------------------
// Overflow cleanup (statistically ~100 edges): global atomics after k_spmm.
// ---------------------------------------------------------------------------
__global__ __launch_bounds__(256) void k_ofl(const ushort* __restrict__ supb,
                                             const int4* __restrict__ ovf,
                                             const int* __restrict__ ocur,
                                             float* __restrict__ out) {
    int n = *ocur;
    if (n > OCAP) n = OCAP;
    const int lane = threadIdx.x & 63;
    const uint* S = (const uint*)supb;
    for (int e = (blockIdx.x * 256 + threadIdx.x) >> 6; e < n; e += 64) {
        int4 rec = ovf[e];
        uint s = S[(size_t)rec.y * 64 + lane];
        float v = __int_as_float(rec.z);
        atomicAdd(&out[(size_t)rec.x * D + 2 * lane],     v * bflo(s));
        atomicAdd(&out[(size_t)rec.x * D + 2 * lane + 1], v * bfhi(s));
    }
}

extern "C" void kernel_launch(void* const* d_in, const int* in_sizes, int n_in,
                              void* d_out, int out_size, void* d_ws, size_t ws_size,
                              hipStream_t stream) {
    const float* x    = (const float*)d_in[0];
    const float* w    = (const float*)d_in[1];
    const float* bias = (const float*)d_in[2];
    const float* ev   = (const float*)d_in[3];
    const int*   er   = (const int*)d_in[4];
    const int*   ec   = (const int*)d_in[5];
    float* out = (float*)d_out;

    // workspace layout (16B aligned), ~59.6 MB
    char* ws = (char*)d_ws;
    ushort* supb   = (ushort*)(ws);                 // 25,600,000
    ushort* wt     = (ushort*)(ws + 25600000);      //     32,768
    int*    counts = (int*)   (ws + 25632768);      //  1,000,960 (G*NBUCK ints)
    int*    ocur   = (int*)   (ws + 26633728);      //         64
    int4*   ovf    = (int4*)  (ws + 26633792);      //    131,072
    int2*   tmp    = (int2*)  (ws + 26764864);      // 32,030,720 (NBUCK*WSLOT*8)
    int2*   rowrg  = (int2*)  (ws + 58795584);      //    800,000
    // end 59,595,584

    k_wt  <<<64, 256, 0, stream>>>(w, wt, ocur);
    k_gemm<<<(N_NODES + 127) / 128, 256, 0, stream>>>(x, wt, supb);

    k_part<<<G, 512, 0, stream>>>(er, ec, ev, tmp, counts, ocur, ovf);
    k_sort<<<NBUCK, 320, 0, stream>>>(tmp, counts, rowrg, ocur, ovf);

    k_spmm<<<(N_NODES + 3) / 4, 256, 0, stream>>>(supb, rowrg, tmp, bias, out);
    k_ofl <<<16, 256, 0, stream>>>(supb, ovf, ocur, out);
}